// Round 1
// baseline (455.724 us; speedup 1.0000x reference)
//
#include <hip/hip_runtime.h>
#include <hip/hip_bf16.h>
#include <cstdint>

typedef uint16_t u16;
typedef __attribute__((ext_vector_type(8))) __bf16 bf16x8;
typedef __attribute__((ext_vector_type(4))) short s16x4;
typedef __attribute__((ext_vector_type(4))) float f32x4;

#define MFMA(a, b, c) __builtin_amdgcn_mfma_f32_16x16x32_bf16((a), (b), (c), 0, 0, 0)

__device__ __forceinline__ u16 f2bf(float f) {
  union { float f; uint32_t u; } v; v.f = f;
  uint32_t u = v.u;
  return (u16)((u + 0x7FFFu + ((u >> 16) & 1u)) >> 16);
}
__device__ __forceinline__ float bf2f(u16 s) {
  union { uint32_t u; float f; } v; v.u = ((uint32_t)s) << 16;
  return v.f;
}

// ---------------- prep kernels ----------------

// Transpose + bf16-convert the four weight matrices.
// WqT/WkT/WvT: [1536][128] (row = out-feature n, col = k) ; WaT: [128][1536]
__global__ void k_prep_w(const float* __restrict__ Wq, const float* __restrict__ Wk,
                         const float* __restrict__ Wv, const float* __restrict__ Wa,
                         u16* __restrict__ WqT, u16* __restrict__ WkT,
                         u16* __restrict__ WvT, u16* __restrict__ WaT) {
  int gid = blockIdx.x * 256 + threadIdx.x;     // < 4*196608
  int m = gid / 196608;
  int e = gid - m * 196608;
  if (m < 3) {
    const float* src = (m == 0) ? Wq : (m == 1) ? Wk : Wv;
    u16* dst = (m == 0) ? WqT : (m == 1) ? WkT : WvT;
    int n = e % 1536, k = e / 1536;             // e = k*1536 + n (coalesced read)
    dst[n * 128 + k] = f2bf(src[e]);
  } else {
    int n = e & 127, k = e >> 7;                // e = k*128 + n
    WaT[n * 1536 + k] = f2bf(Wa[e]);
  }
}

// MLP bias table (225 x 4) + per-head temperature
__global__ void k_table(const float* __restrict__ rpos, const float* __restrict__ w1,
                        const float* __restrict__ b1, const float* __restrict__ w2,
                        const float* __restrict__ ls, float* __restrict__ table,
                        float* __restrict__ temp) {
  int t = threadIdx.x;
  if (t < 225) {
    float x0 = rpos[t * 2 + 0], x1 = rpos[t * 2 + 1];
    float a0 = 0.f, a1 = 0.f, a2 = 0.f, a3 = 0.f;
    for (int c = 0; c < 512; ++c) {
      float hv = fmaxf(fmaf(x0, w1[c], fmaf(x1, w1[512 + c], b1[c])), 0.f);
      a0 = fmaf(hv, w2[c * 4 + 0], a0);
      a1 = fmaf(hv, w2[c * 4 + 1], a1);
      a2 = fmaf(hv, w2[c * 4 + 2], a2);
      a3 = fmaf(hv, w2[c * 4 + 3], a3);
    }
    table[t * 4 + 0] = a0; table[t * 4 + 1] = a1;
    table[t * 4 + 2] = a2; table[t * 4 + 3] = a3;
  }
  if (t < 4) temp[t] = expf(fminf(ls[t], 4.6051701859880914f));
}

// biasT[h][q][p] = 16*sigmoid(table[rel_idx[...]][h]) with the reference's
// einops scramble: p = ih*8+jh, q = iw*8+jw, i = ih*8+iw, j = jh*8+jw
__global__ void k_bias(const int* __restrict__ ridx, const float* __restrict__ table,
                       float* __restrict__ biasT) {
  int gid = blockIdx.x * 256 + threadIdx.x;     // < 16384
  int h = gid >> 12;
  int rem = gid & 4095;
  int q = rem >> 6, p = rem & 63;
  int ii = ((p >> 3) << 3) + (q >> 3);
  int jj = ((p & 7) << 3) + (q & 7);
  int ri = ridx[ii * 64 + jj];
  float v = table[ri * 4 + h];
  biasT[gid] = 16.f / (1.f + expf(-v));
}

// ---------------- main fused kernel ----------------
// 1 block = 1 window (b). 512 threads = 8 waves. All heads looped in-block.
__global__ __launch_bounds__(512) void k_msa(
    const float* __restrict__ E,
    const u16* __restrict__ WqT, const u16* __restrict__ WkT,
    const u16* __restrict__ WvT, const u16* __restrict__ WaT,
    const float* __restrict__ biasT, const float* __restrict__ temp,
    const float* __restrict__ Qb, const float* __restrict__ Vb,
    const float* __restrict__ Ab, float* __restrict__ out) {
  __shared__ __align__(16) u16 sE[64 * 136];    // E tile (bf16), pad 128->136
  __shared__ __align__(16) u16 sB1[64 * 392];   // Q, later A   (pad 384->392)
  __shared__ __align__(16) u16 sB2[27648];      // K [64][392], later V^T [384][72]
  __shared__ __align__(16) u16 sP[64 * 72];     // P (bf16), pad 64->72
  __shared__ __align__(16) float sQs[64];       // temp/||q_i||
  __shared__ __align__(16) float sKi[64];       // 1/||k_j||

  const int tid = threadIdx.x;
  const int wid = tid >> 6;
  const int lane = tid & 63;
  const int l15 = lane & 15;
  const int lk4 = (lane >> 4) << 2;   // C-frag row base
  const int lk8 = (lane >> 4) << 3;   // A/B-frag k base
  const int b = blockIdx.x;

  // ---- stage E (f32 -> bf16, padded)
  {
    const float4* Eb = (const float4*)(E + (size_t)b * 8192);
    #pragma unroll
    for (int it = 0; it < 4; ++it) {
      int i = tid + it * 512;         // 2048 float4s
      float4 v = Eb[i];
      int row = i >> 5;
      int c = (i & 31) << 2;
      s16x4 u;
      u[0] = (short)f2bf(v.x); u[1] = (short)f2bf(v.y);
      u[2] = (short)f2bf(v.z); u[3] = (short)f2bf(v.w);
      *(s16x4*)&sE[row * 136 + c] = u;
    }
  }

  const f32x4 zf4 = {0.f, 0.f, 0.f, 0.f};
  f32x4 oacc[4];
  #pragma unroll
  for (int n = 0; n < 4; ++n) oacc[n] = zf4;
  const int omt = wid >> 1;           // out m-tile (0..3)
  const int ont0 = (wid & 1) * 4;     // out n-tile base (of 8)

  for (int h = 0; h < 4; ++h) {
    __syncthreads();
    // ---- Q (waves 0-3) / K (waves 4-7) projection: 64x384 = E(64x128) @ W
    {
      const u16* WT = (wid < 4) ? WqT : WkT;
      u16* dst = (wid < 4) ? sB1 : sB2;
      const int nc0 = (wid & 3) * 96;           // column base
      f32x4 acc[6][4];
      #pragma unroll
      for (int n = 0; n < 6; ++n)
        #pragma unroll
        for (int m = 0; m < 4; ++m) acc[n][m] = zf4;
      #pragma unroll
      for (int ks = 0; ks < 4; ++ks) {
        const int koff = ks * 32 + lk8;
        bf16x8 a[4];
        #pragma unroll
        for (int m = 0; m < 4; ++m)
          a[m] = *(const bf16x8*)&sE[(m * 16 + l15) * 136 + koff];
        bf16x8 bw[6];
        #pragma unroll
        for (int n = 0; n < 6; ++n)
          bw[n] = *(const bf16x8*)&WT[(size_t)(h * 384 + nc0 + n * 16 + l15) * 128 + koff];
        #pragma unroll
        for (int n = 0; n < 6; ++n)
          #pragma unroll
          for (int m = 0; m < 4; ++m)
            acc[n][m] = MFMA(a[m], bw[n], acc[n][m]);
      }
      #pragma unroll
      for (int n = 0; n < 6; ++n) {
        const int col = nc0 + n * 16 + l15;
        const float bv = (wid < 4) ? Qb[h * 384 + col] : 0.0f;
        #pragma unroll
        for (int m = 0; m < 4; ++m) {
          const int r0 = m * 16 + lk4;
          #pragma unroll
          for (int r = 0; r < 4; ++r)
            dst[(r0 + r) * 392 + col] = f2bf(acc[n][m][r] + bv);
        }
      }
    }
    __syncthreads();
    // ---- row norms of Q and K (8 partials per row, shuffle-reduced)
    {
      const float th = temp[h];
      #pragma unroll
      for (int rep = 0; rep < 2; ++rep) {
        const int job = tid + rep * 512;
        const int rowid = job >> 3;
        const int p = job & 7;
        const u16* src = (rowid < 64) ? &sB1[rowid * 392 + p * 48]
                                      : &sB2[(rowid - 64) * 392 + p * 48];
        float s = 0.f;
        #pragma unroll
        for (int jj = 0; jj < 6; ++jj) {
          bf16x8 v = *(const bf16x8*)&src[jj * 8];
          #pragma unroll
          for (int e = 0; e < 8; ++e) {
            float f = (float)v[e];
            s = fmaf(f, f, s);
          }
        }
        s += __shfl_xor(s, 1);
        s += __shfl_xor(s, 2);
        s += __shfl_xor(s, 4);
        if (p == 0) {
          float nr = fmaxf(sqrtf(s), 1e-12f);
          if (rowid < 64) sQs[rowid] = th / nr;
          else            sKi[rowid - 64] = 1.0f / nr;
        }
      }
    }
    __syncthreads();
    // ---- S = Q K^T (64x64, K=384) -> P = S*qs*ki + bias (bf16)
    {
      const int mt = wid >> 1;
      const int j0 = (wid & 1) * 32;
      f32x4 acc[2] = {zf4, zf4};
      #pragma unroll
      for (int ks = 0; ks < 12; ++ks) {
        const int koff = ks * 32 + lk8;
        bf16x8 a = *(const bf16x8*)&sB1[(mt * 16 + l15) * 392 + koff];
        #pragma unroll
        for (int n = 0; n < 2; ++n) {
          bf16x8 bw = *(const bf16x8*)&sB2[(j0 + n * 16 + l15) * 392 + koff];
          acc[n] = MFMA(a, bw, acc[n]);
        }
      }
      const int i0 = mt * 16 + lk4;
      const f32x4 qs4 = *(const f32x4*)&sQs[i0];
      #pragma unroll
      for (int n = 0; n < 2; ++n) {
        const int j = j0 + n * 16 + l15;
        const float kj = sKi[j];
        const f32x4 bb = *(const f32x4*)&biasT[h * 4096 + j * 64 + i0];
        #pragma unroll
        for (int r = 0; r < 4; ++r)
          sP[(i0 + r) * 72 + j] = f2bf(fmaf(acc[n][r] * qs4[r], kj, bb[r]));
      }
    }
    __syncthreads();
    // ---- V projection, stored transposed: V^T[384][72] into sB2
    {
      const int nc0 = wid * 48;
      f32x4 acc[3][4];
      #pragma unroll
      for (int n = 0; n < 3; ++n)
        #pragma unroll
        for (int m = 0; m < 4; ++m) acc[n][m] = zf4;
      #pragma unroll
      for (int ks = 0; ks < 4; ++ks) {
        const int koff = ks * 32 + lk8;
        bf16x8 a[4];
        #pragma unroll
        for (int m = 0; m < 4; ++m)
          a[m] = *(const bf16x8*)&sE[(m * 16 + l15) * 136 + koff];
        bf16x8 bw[3];
        #pragma unroll
        for (int n = 0; n < 3; ++n)
          bw[n] = *(const bf16x8*)&WvT[(size_t)(h * 384 + nc0 + n * 16 + l15) * 128 + koff];
        #pragma unroll
        for (int n = 0; n < 3; ++n)
          #pragma unroll
          for (int m = 0; m < 4; ++m)
            acc[n][m] = MFMA(a[m], bw[n], acc[n][m]);
      }
      #pragma unroll
      for (int n = 0; n < 3; ++n) {
        const int col = nc0 + n * 16 + l15;       // feature index
        const float bv = Vb[h * 384 + col];
        #pragma unroll
        for (int m = 0; m < 4; ++m) {
          const int r0 = m * 16 + lk4;            // window-pos base
          s16x4 u;
          u[0] = (short)f2bf(acc[n][m][0] + bv);
          u[1] = (short)f2bf(acc[n][m][1] + bv);
          u[2] = (short)f2bf(acc[n][m][2] + bv);
          u[3] = (short)f2bf(acc[n][m][3] + bv);
          *(s16x4*)&sB2[col * 72 + r0] = u;
        }
      }
    }
    __syncthreads();
    // ---- A = P @ V  (64x384, K=64) -> sB1 (bf16)
    {
      const int nc0 = wid * 48;
      f32x4 acc[3][4];
      #pragma unroll
      for (int n = 0; n < 3; ++n)
        #pragma unroll
        for (int m = 0; m < 4; ++m) acc[n][m] = zf4;
      #pragma unroll
      for (int ks = 0; ks < 2; ++ks) {
        const int koff = ks * 32 + lk8;
        bf16x8 a[4];
        #pragma unroll
        for (int m = 0; m < 4; ++m)
          a[m] = *(const bf16x8*)&sP[(m * 16 + l15) * 72 + koff];
        bf16x8 bw[3];
        #pragma unroll
        for (int n = 0; n < 3; ++n)
          bw[n] = *(const bf16x8*)&sB2[(nc0 + n * 16 + l15) * 72 + koff];
        #pragma unroll
        for (int n = 0; n < 3; ++n)
          #pragma unroll
          for (int m = 0; m < 4; ++m)
            acc[n][m] = MFMA(a[m], bw[n], acc[n][m]);
      }
      #pragma unroll
      for (int n = 0; n < 3; ++n) {
        const int col = nc0 + n * 16 + l15;
        #pragma unroll
        for (int m = 0; m < 4; ++m) {
          const int r0 = m * 16 + lk4;
          #pragma unroll
          for (int r = 0; r < 4; ++r)
            sB1[(r0 + r) * 392 + col] = f2bf(acc[n][m][r]);
        }
      }
    }
    __syncthreads();
    // ---- OUT += A @ Wa_h   (64x128, K=384), accumulated across heads
    {
      #pragma unroll
      for (int ks = 0; ks < 12; ++ks) {
        const int koff = ks * 32 + lk8;
        bf16x8 a = *(const bf16x8*)&sB1[(omt * 16 + l15) * 392 + koff];
        #pragma unroll
        for (int n = 0; n < 4; ++n) {
          bf16x8 bw = *(const bf16x8*)&WaT[(size_t)((ont0 + n) * 16 + l15) * 1536 + h * 384 + koff];
          oacc[n] = MFMA(a, bw, oacc[n]);
        }
      }
    }
  }

  // ---- epilogue: + bias, f32 store
  {
    float* ob = out + (size_t)b * 8192;
    #pragma unroll
    for (int n = 0; n < 4; ++n) {
      const int col = (ont0 + n) * 16 + l15;
      const float bv = Ab[col];
      #pragma unroll
      for (int r = 0; r < 4; ++r)
        ob[(omt * 16 + lk4 + r) * 128 + col] = oacc[n][r] + bv;
    }
  }
}

// ---------------- host ----------------
extern "C" void kernel_launch(void* const* d_in, const int* in_sizes, int n_in,
                              void* d_out, int out_size, void* d_ws, size_t ws_size,
                              hipStream_t stream) {
  const float* E    = (const float*)d_in[0];
  const float* rpos = (const float*)d_in[1];
  const int*   ridx = (const int*)d_in[2];
  const float* Wq   = (const float*)d_in[3];
  const float* Qb   = (const float*)d_in[4];
  const float* Wk   = (const float*)d_in[5];
  const float* Wv   = (const float*)d_in[6];
  const float* Vb   = (const float*)d_in[7];
  const float* Wa   = (const float*)d_in[8];
  const float* Ab   = (const float*)d_in[9];
  const float* w1   = (const float*)d_in[10];
  const float* b1   = (const float*)d_in[11];
  const float* w2   = (const float*)d_in[12];
  const float* ls   = (const float*)d_in[13];

  char* ws = (char*)d_ws;
  u16* WqT = (u16*)(ws + 0);
  u16* WkT = (u16*)(ws + 393216);
  u16* WvT = (u16*)(ws + 786432);
  u16* WaT = (u16*)(ws + 1179648);
  float* biasT = (float*)(ws + 1572864);
  float* table = (float*)(ws + 1638400);
  float* temp  = (float*)(ws + 1642496);

  k_prep_w<<<3072, 256, 0, stream>>>(Wq, Wk, Wv, Wa, WqT, WkT, WvT, WaT);
  k_table<<<1, 256, 0, stream>>>(rpos, w1, b1, w2, ls, table, temp);
  k_bias<<<64, 256, 0, stream>>>(ridx, table, biasT);
  k_msa<<<1024, 512, 0, stream>>>(E, WqT, WkT, WvT, WaT, biasT, temp,
                                  Qb, Vb, Ab, (float*)d_out);
}

// Round 2
// 247.745 us; speedup vs baseline: 1.8395x; 1.8395x over previous
//
#include <hip/hip_runtime.h>
#include <hip/hip_bf16.h>
#include <cstdint>

typedef uint16_t u16;
typedef __attribute__((ext_vector_type(8))) __bf16 bf16x8;
typedef __attribute__((ext_vector_type(4))) short s16x4;
typedef __attribute__((ext_vector_type(4))) float f32x4;

#define MFMA(a, b, c) __builtin_amdgcn_mfma_f32_16x16x32_bf16((a), (b), (c), 0, 0, 0)

__device__ __forceinline__ u16 f2bf(float f) {
  union { float f; uint32_t u; } v; v.f = f;
  uint32_t u = v.u;
  return (u16)((u + 0x7FFFu + ((u >> 16) & 1u)) >> 16);
}
__device__ __forceinline__ float bf2f(u16 s) {
  union { uint32_t u; float f; } v; v.u = ((uint32_t)s) << 16;
  return v.f;
}

// ---------------- prep kernels ----------------

// bf16 conversions: Wq/Wk/Wv [128][1536] same-layout; Wa [1536][128] -> WaT [128][1536]
__global__ void k_prep_w(const float* __restrict__ Wq, const float* __restrict__ Wk,
                         const float* __restrict__ Wv, const float* __restrict__ Wa,
                         u16* __restrict__ Wqb, u16* __restrict__ Wkb,
                         u16* __restrict__ Wvb, u16* __restrict__ WaTb) {
  int gid = blockIdx.x * 256 + threadIdx.x;     // < 4*196608
  int m = gid / 196608;
  int e = gid - m * 196608;
  if (m == 0)      Wqb[e] = f2bf(Wq[e]);
  else if (m == 1) Wkb[e] = f2bf(Wk[e]);
  else if (m == 2) Wvb[e] = f2bf(Wv[e]);
  else {
    int n = e & 127, k = e >> 7;                // e = k*128 + n
    WaTb[n * 1536 + k] = f2bf(Wa[e]);
  }
}

// MLP bias table (225 x 4) + per-head temperature
__global__ void k_table(const float* __restrict__ rpos, const float* __restrict__ w1,
                        const float* __restrict__ b1, const float* __restrict__ w2,
                        const float* __restrict__ ls, float* __restrict__ table,
                        float* __restrict__ temp) {
  int t = threadIdx.x;
  if (t < 225) {
    float x0 = rpos[t * 2 + 0], x1 = rpos[t * 2 + 1];
    float a0 = 0.f, a1 = 0.f, a2 = 0.f, a3 = 0.f;
    for (int c = 0; c < 512; ++c) {
      float hv = fmaxf(fmaf(x0, w1[c], fmaf(x1, w1[512 + c], b1[c])), 0.f);
      a0 = fmaf(hv, w2[c * 4 + 0], a0);
      a1 = fmaf(hv, w2[c * 4 + 1], a1);
      a2 = fmaf(hv, w2[c * 4 + 2], a2);
      a3 = fmaf(hv, w2[c * 4 + 3], a3);
    }
    table[t * 4 + 0] = a0; table[t * 4 + 1] = a1;
    table[t * 4 + 2] = a2; table[t * 4 + 3] = a3;
  }
  if (t < 4) temp[t] = expf(fminf(ls[t], 4.6051701859880914f));
}

// biasT[h][q][p] = 16*sigmoid(table[rel_idx[...]][h]) (einops scramble as in ref)
__global__ void k_bias(const int* __restrict__ ridx, const float* __restrict__ table,
                       float* __restrict__ biasT) {
  int gid = blockIdx.x * 256 + threadIdx.x;     // < 16384
  int h = gid >> 12;
  int rem = gid & 4095;
  int q = rem >> 6, p = rem & 63;
  int ii = ((p >> 3) << 3) + (q >> 3);
  int jj = ((p & 7) << 3) + (q & 7);
  int ri = ridx[ii * 64 + jj];
  float v = table[ri * 4 + h];
  biasT[gid] = 16.f / (1.f + expf(-v));
}

// Gram-type matrices, all 128x128 with K=384:
//  t=0: M = Wq_h Wk_h^T  -> BigB[h][l in 0..127][e=k], row e=128 = u = Wk_h qb_h
//  t=1: Gq = Wq Wq^T     -> BigB[h][128+l][k],        row e=128 = 2*Wq_h qb_h
//  t=2: Gk = Wk Wk^T     -> BigB[h][256+l][k],        row e=128 = 0
//  t=3: N  = Wv_h Wa_h   -> NT[c][h*128+k];  w4[h][c] = Wa_h^T vb_h
__global__ void k_gram(const u16* __restrict__ Wqb, const u16* __restrict__ Wkb,
                       const u16* __restrict__ Wvb, const u16* __restrict__ WaTb,
                       const float* __restrict__ Wq, const float* __restrict__ Wk,
                       const float* __restrict__ Wa,
                       const float* __restrict__ Qb, const float* __restrict__ Vb,
                       u16* __restrict__ BigB, u16* __restrict__ NT,
                       float* __restrict__ w4, float* __restrict__ cq4) {
  const int h = blockIdx.x >> 2, t = blockIdx.x & 3;
  const int tid = threadIdx.x;
  const int wid = tid >> 6, lane = tid & 63;
  const int l15 = lane & 15, lk4 = (lane >> 4) << 2, lk8 = (lane >> 4) << 3;
  const u16* Am = (t == 3) ? Wvb : (t == 2) ? Wkb : Wqb;
  const u16* Bm = (t == 1) ? Wqb : (t == 3) ? WaTb : Wkb;
  const f32x4 zf4 = {0.f, 0.f, 0.f, 0.f};
  f32x4 acc[2][8];
  #pragma unroll
  for (int mm = 0; mm < 2; ++mm)
    #pragma unroll
    for (int nn = 0; nn < 8; ++nn) acc[mm][nn] = zf4;
  #pragma unroll
  for (int ks = 0; ks < 12; ++ks) {
    const int koff = h * 384 + ks * 32 + lk8;
    bf16x8 a[2], bw[8];
    #pragma unroll
    for (int mm = 0; mm < 2; ++mm)
      a[mm] = *(const bf16x8*)&Am[(size_t)(wid * 32 + mm * 16 + l15) * 1536 + koff];
    #pragma unroll
    for (int nn = 0; nn < 8; ++nn)
      bw[nn] = *(const bf16x8*)&Bm[(size_t)(nn * 16 + l15) * 1536 + koff];
    #pragma unroll
    for (int nn = 0; nn < 8; ++nn)
      #pragma unroll
      for (int mm = 0; mm < 2; ++mm)
        acc[mm][nn] = MFMA(a[mm], bw[nn], acc[mm][nn]);
  }
  #pragma unroll
  for (int mm = 0; mm < 2; ++mm) {
    const int k0 = wid * 32 + mm * 16 + lk4;
    #pragma unroll
    for (int nn = 0; nn < 8; ++nn) {
      const int l = nn * 16 + l15;
      s16x4 u;
      u[0] = (short)f2bf(acc[mm][nn][0]); u[1] = (short)f2bf(acc[mm][nn][1]);
      u[2] = (short)f2bf(acc[mm][nn][2]); u[3] = (short)f2bf(acc[mm][nn][3]);
      if (t < 3) *(s16x4*)&BigB[(size_t)(h * 384 + t * 128 + l) * 160 + k0] = u;
      else       *(s16x4*)&NT[(size_t)l * 512 + h * 128 + k0] = u;
    }
  }
  // augmented row e=128 + zero-fill e=129..159 ; w4 ; cq4
  if (t < 3) {
    for (int l = tid; l < 128; l += 256) {
      float s = 0.f;
      if (t == 0) { for (int f = 0; f < 384; ++f) s += Wk[(size_t)l * 1536 + h * 384 + f] * Qb[h * 384 + f]; }
      else if (t == 1) { for (int f = 0; f < 384; ++f) s += 2.f * Wq[(size_t)l * 1536 + h * 384 + f] * Qb[h * 384 + f]; }
      u16* row = &BigB[(size_t)(h * 384 + t * 128 + l) * 160];
      row[128] = f2bf(s);
      for (int e = 129; e < 160; ++e) row[e] = 0;
    }
    if (t == 0 && tid == 0) {
      float s = 0.f;
      for (int f = 0; f < 384; ++f) s += Qb[h * 384 + f] * Qb[h * 384 + f];
      cq4[h] = s;
    }
  } else {
    for (int c = tid; c < 128; c += 256) {
      float s = 0.f;
      for (int f = 0; f < 384; ++f) s += Vb[h * 384 + f] * Wa[(size_t)(h * 384 + f) * 128 + c];
      w4[h * 128 + c] = s;
    }
  }
}

// ---------------- main fused kernel ----------------
// 1 block = 1 window. 512 threads = 8 waves. ~66 KB LDS -> 2 blocks/CU.
__global__ __launch_bounds__(512, 4) void k_msa(
    const float* __restrict__ E,
    const u16* __restrict__ BigB, const u16* __restrict__ NT,
    const float* __restrict__ biasT, const float* __restrict__ temp,
    const float* __restrict__ w4, const float* __restrict__ cq4,
    const float* __restrict__ Ab, float* __restrict__ out) {
  __shared__ __align__(16) u16 sE[64 * 168];    // Ê: cols 0..127=E, 128=1, 129..159=0
  __shared__ __align__(16) u16 sET[128 * 72];   // E^T [f][j]
  __shared__ __align__(16) u16 sT1[64 * 136];   // T1, then PE
  __shared__ __align__(16) u16 sP[64 * 72];     // P (bf16)
  __shared__ float sDq[64], sDk[64];            // diag accumulators
  __shared__ float sRSp[2][64];                 // rowsum(P) partials

  const int tid = threadIdx.x;
  const int wid = tid >> 6;
  const int lane = tid & 63;
  const int l15 = lane & 15;
  const int lk4 = (lane >> 4) << 2;
  const int lk8 = (lane >> 4) << 3;
  const int b = blockIdx.x;
  const float* Eb = E + (size_t)b * 8192;

  // ---- stage Ê, E^T ; zero diag accumulators
  {
    const float4* E4 = (const float4*)Eb;
    #pragma unroll
    for (int it = 0; it < 4; ++it) {
      int i = tid + it * 512;                   // 2048 float4
      float4 v = E4[i];
      int row = i >> 5, c = (i & 31) << 2;
      s16x4 u;
      u[0] = (short)f2bf(v.x); u[1] = (short)f2bf(v.y);
      u[2] = (short)f2bf(v.z); u[3] = (short)f2bf(v.w);
      *(s16x4*)&sE[row * 168 + c] = u;
    }
    {
      int row = tid >> 3, p = tid & 7;          // aug cols 128..159
      s16x4 zz = {0, 0, 0, 0};
      if (p == 0) zz[0] = (short)0x3F80;        // bf16(1.0)
      *(s16x4*)&sE[row * 168 + 128 + p * 4] = zz;
    }
    {
      int f = tid & 127, j0 = (tid >> 7) << 4;  // transpose staging
      #pragma unroll
      for (int q = 0; q < 4; ++q) {
        s16x4 u;
        #pragma unroll
        for (int e = 0; e < 4; ++e) u[e] = (short)f2bf(Eb[(j0 + q * 4 + e) * 128 + f]);
        *(s16x4*)&sET[f * 72 + j0 + q * 4] = u;
      }
    }
    if (tid < 64) sDq[tid] = 0.f;
    else if (tid < 128) sDk[tid - 64] = 0.f;
  }
  __syncthreads();

  const f32x4 zf4 = {0.f, 0.f, 0.f, 0.f};
  f32x4 oacc[4];
  #pragma unroll
  for (int m = 0; m < 4; ++m) oacc[m] = zf4;
  const int onc = wid << 4;                     // this wave's output col strip

  for (int h = 0; h < 4; ++h) {
    const float th = temp[h], cqh = cq4[h];
    // ---- P1: Y = Ê @ BigB_h^T cols [T1 | Zq | Zk], K=160
    {
      const int nc0 = wid * 48;
      f32x4 acc[3][4];
      #pragma unroll
      for (int n = 0; n < 3; ++n)
        #pragma unroll
        for (int m = 0; m < 4; ++m) acc[n][m] = zf4;
      #pragma unroll
      for (int ks = 0; ks < 5; ++ks) {
        const int koff = ks * 32 + lk8;
        bf16x8 a[4], bw[3];
        #pragma unroll
        for (int m = 0; m < 4; ++m)
          a[m] = *(const bf16x8*)&sE[(m * 16 + l15) * 168 + koff];
        #pragma unroll
        for (int n = 0; n < 3; ++n)
          bw[n] = *(const bf16x8*)&BigB[(size_t)(h * 384 + nc0 + n * 16 + l15) * 160 + koff];
        #pragma unroll
        for (int n = 0; n < 3; ++n)
          #pragma unroll
          for (int m = 0; m < 4; ++m)
            acc[n][m] = MFMA(a[m], bw[n], acc[n][m]);
      }
      #pragma unroll
      for (int n = 0; n < 3; ++n) {
        const int col0 = nc0 + n * 16;
        if (col0 < 128) {                       // T1 tile
          const int col = col0 + l15;
          #pragma unroll
          for (int m = 0; m < 4; ++m)
            #pragma unroll
            for (int r = 0; r < 4; ++r)
              sT1[(m * 16 + lk4 + r) * 136 + col] = f2bf(acc[n][m][r]);
        } else {                                // diag(Z * E) accumulation
          const int fb = col0 - ((col0 < 256) ? 128 : 256);
          float* tgt = (col0 < 256) ? sDq : sDk;
          const int ff = fb + l15;
          #pragma unroll
          for (int m = 0; m < 4; ++m) {
            #pragma unroll
            for (int r = 0; r < 4; ++r) {
              float p = acc[n][m][r] * bf2f(sE[(m * 16 + lk4 + r) * 168 + ff]);
              p += __shfl_xor(p, 1); p += __shfl_xor(p, 2);
              p += __shfl_xor(p, 4); p += __shfl_xor(p, 8);
              if (l15 == 0) atomicAdd(&tgt[m * 16 + lk4 + r], p);
            }
          }
        }
      }
    }
    __syncthreads();
    // ---- P2: S = T1 @ E^T (K=128) -> P = S*qs*ki + bias ; rowsum partials
    {
      const int mt = wid >> 1, j0 = (wid & 1) * 32;
      f32x4 acc[2] = {zf4, zf4};
      #pragma unroll
      for (int ks = 0; ks < 4; ++ks) {
        const int koff = ks * 32 + lk8;
        bf16x8 a = *(const bf16x8*)&sT1[(mt * 16 + l15) * 136 + koff];
        #pragma unroll
        for (int n = 0; n < 2; ++n) {
          bf16x8 bw = *(const bf16x8*)&sE[(j0 + n * 16 + l15) * 168 + koff];
          acc[n] = MFMA(a, bw, acc[n]);
        }
      }
      const int i0 = mt * 16 + lk4;
      float qs[4];
      #pragma unroll
      for (int r = 0; r < 4; ++r) {
        float dq = fmaxf(sDq[i0 + r] + cqh, 0.f);
        qs[r] = th / fmaxf(sqrtf(dq), 1e-12f);
      }
      float pv[2][4];
      #pragma unroll
      for (int n = 0; n < 2; ++n) {
        const int j = j0 + n * 16 + l15;
        const float ki = 1.f / fmaxf(sqrtf(fmaxf(sDk[j], 0.f)), 1e-12f);
        const f32x4 bb = *(const f32x4*)&biasT[h * 4096 + j * 64 + i0];
        #pragma unroll
        for (int r = 0; r < 4; ++r) {
          pv[n][r] = fmaf(acc[n][r] * qs[r], ki, bb[r]);
          sP[(i0 + r) * 72 + j] = f2bf(pv[n][r]);
        }
      }
      #pragma unroll
      for (int r = 0; r < 4; ++r) {
        float ps = pv[0][r] + pv[1][r];
        ps += __shfl_xor(ps, 1); ps += __shfl_xor(ps, 2);
        ps += __shfl_xor(ps, 4); ps += __shfl_xor(ps, 8);
        if (l15 == 0) sRSp[wid & 1][i0 + r] = ps;
      }
    }
    __syncthreads();
    // ---- P3: PE = P @ E (K=64) -> sT1 ; re-zero diag accumulators
    {
      const int nc0 = wid << 4;
      f32x4 acc[4] = {zf4, zf4, zf4, zf4};
      #pragma unroll
      for (int ks = 0; ks < 2; ++ks) {
        const int koff = ks * 32 + lk8;
        bf16x8 bw = *(const bf16x8*)&sET[(nc0 + l15) * 72 + koff];
        #pragma unroll
        for (int m = 0; m < 4; ++m) {
          bf16x8 a = *(const bf16x8*)&sP[(m * 16 + l15) * 72 + koff];
          acc[m] = MFMA(a, bw, acc[m]);
        }
      }
      #pragma unroll
      for (int m = 0; m < 4; ++m)
        #pragma unroll
        for (int r = 0; r < 4; ++r)
          sT1[(m * 16 + lk4 + r) * 136 + nc0 + l15] = f2bf(acc[m][r]);
      if (tid < 64) sDq[tid] = 0.f;
      else if (tid < 128) sDk[tid - 64] = 0.f;
    }
    __syncthreads();
    // ---- P4: out += PE @ N_h (K=128) + rowsum(P)*w_h
    {
      const float wv = w4[h * 128 + onc + l15];
      #pragma unroll
      for (int ks = 0; ks < 4; ++ks) {
        const int koff = ks * 32 + lk8;
        bf16x8 bw = *(const bf16x8*)&NT[(size_t)(onc + l15) * 512 + h * 128 + koff];
        #pragma unroll
        for (int m = 0; m < 4; ++m) {
          bf16x8 a = *(const bf16x8*)&sT1[(m * 16 + l15) * 136 + koff];
          oacc[m] = MFMA(a, bw, oacc[m]);
        }
      }
      #pragma unroll
      for (int m = 0; m < 4; ++m)
        #pragma unroll
        for (int r = 0; r < 4; ++r) {
          const int i = m * 16 + lk4 + r;
          oacc[m][r] = fmaf(sRSp[0][i] + sRSp[1][i], wv, oacc[m][r]);
        }
    }
    __syncthreads();
  }

  // ---- epilogue: + out-proj bias, f32 store
  {
    float* ob = out + (size_t)b * 8192;
    const float bv = Ab[onc + l15];
    #pragma unroll
    for (int m = 0; m < 4; ++m)
      #pragma unroll
      for (int r = 0; r < 4; ++r)
        ob[(m * 16 + lk4 + r) * 128 + onc + l15] = oacc[m][r] + bv;
  }
}

// ---------------- host ----------------
extern "C" void kernel_launch(void* const* d_in, const int* in_sizes, int n_in,
                              void* d_out, int out_size, void* d_ws, size_t ws_size,
                              hipStream_t stream) {
  const float* E    = (const float*)d_in[0];
  const float* rpos = (const float*)d_in[1];
  const int*   ridx = (const int*)d_in[2];
  const float* Wq   = (const float*)d_in[3];
  const float* Qb   = (const float*)d_in[4];
  const float* Wk   = (const float*)d_in[5];
  const float* Wv   = (const float*)d_in[6];
  const float* Vb   = (const float*)d_in[7];
  const float* Wa   = (const float*)d_in[8];
  const float* Ab   = (const float*)d_in[9];
  const float* w1   = (const float*)d_in[10];
  const float* b1   = (const float*)d_in[11];
  const float* w2   = (const float*)d_in[12];
  const float* ls   = (const float*)d_in[13];

  char* ws = (char*)d_ws;
  u16* Wqb   = (u16*)(ws + 0);
  u16* Wkb   = (u16*)(ws + 393216);
  u16* Wvb   = (u16*)(ws + 786432);
  u16* WaTb  = (u16*)(ws + 1179648);
  u16* BigB  = (u16*)(ws + 1572864);   // 4*384*160*2 = 491520
  u16* NT    = (u16*)(ws + 2064384);   // 128*512*2   = 131072
  float* biasT = (float*)(ws + 2195456); // 65536
  float* table = (float*)(ws + 2260992); // 4096
  float* temp  = (float*)(ws + 2265088); // 64
  float* w4    = (float*)(ws + 2265152); // 2048
  float* cq4   = (float*)(ws + 2267200); // 64

  k_prep_w<<<3072, 256, 0, stream>>>(Wq, Wk, Wv, Wa, Wqb, Wkb, Wvb, WaTb);
  k_table<<<1, 256, 0, stream>>>(rpos, w1, b1, w2, ls, table, temp);
  k_gram<<<16, 256, 0, stream>>>(Wqb, Wkb, Wvb, WaTb, Wq, Wk, Wa, Qb, Vb,
                                 BigB, NT, w4, cq4);
  k_bias<<<64, 256, 0, stream>>>(ridx, table, biasT);
  k_msa<<<1024, 512, 0, stream>>>(E, BigB, NT, biasT, temp, w4, cq4, Ab,
                                  (float*)d_out);
}